// Round 5
// baseline (2342.044 us; speedup 1.0000x reference)
//
#include <hip/hip_runtime.h>

#define N_NODES 8192
#define N_EDGES 131072
#define NGRAPH  64
#define DIM     32
#define HID     128
#define KHALF   64         // k per half-block
#define G_NODES 4          // nodes per block
#define SROW    36         // S d-stride (16B-aligned, used with d-rotation swizzle)
#define HROW    68         // hidb edge stride (bank-spread for staging writes)
#define OROW    36         // osrcb edge stride
#define CEDGE   64         // staged edges per chunk
#define S2S_CAP 384

__device__ __forceinline__ float sigmoidf_(float x) { return 1.0f / (1.0f + expf(-x)); }

// ---------------- prep ----------------
// blocks [0,1024): init node features; blocks [1024,1536): degree histogram
__global__ void prep1_kernel(const float* __restrict__ x, const float* __restrict__ w,
                             const float* __restrict__ b, float* __restrict__ out,
                             const int* __restrict__ dst, int* __restrict__ counts) {
  const int bb = blockIdx.x;
  if (bb < 1024) {
    int idx = bb * 256 + threadIdx.x;
    int n = idx >> 5, d = idx & 31;
    out[idx] = fmaxf(fmaf(x[n], w[d], b[d]), 0.0f);
  } else {
    int e = (bb - 1024) * 256 + threadIdx.x;
    atomicAdd(&counts[dst[e]], 1);
  }
}

__global__ void scan_kernel(const int* __restrict__ counts,
                            int* __restrict__ offsets,
                            float* __restrict__ deg_inv) {
  __shared__ int sm[1024];
  int t = threadIdx.x;
  int base = t * 8;
  int loc[8];
  int s = 0;
#pragma unroll
  for (int i = 0; i < 8; ++i) { loc[i] = s; s += counts[base + i]; }
  sm[t] = s;
  __syncthreads();
  for (int off = 1; off < 1024; off <<= 1) {
    int v = (t >= off) ? sm[t - off] : 0;
    __syncthreads();
    sm[t] += v;
    __syncthreads();
  }
  int excl = (t > 0) ? sm[t - 1] : 0;
#pragma unroll
  for (int i = 0; i < 8; ++i) {
    offsets[base + i] = excl + loc[i];
    int c = counts[base + i];
    deg_inv[base + i] = 1.0f / (float)(c > 0 ? c : 1);
  }
  if (t == 1023) offsets[N_NODES] = sm[1023];
}

// blocks [0,512): CSR scatter; blocks [512,544): graph-start table
__global__ void prep2_kernel(const int* __restrict__ ei, const float* __restrict__ ea,
                             const int* __restrict__ offsets, int* __restrict__ cursor,
                             int* __restrict__ csr_src, float2* __restrict__ csr_ea,
                             const int* __restrict__ batch, int* __restrict__ gstart) {
  const int bb = blockIdx.x;
  if (bb < 512) {
    int e = bb * 256 + threadIdx.x;
    int d = ei[N_EDGES + e];
    int pos = atomicAdd(&cursor[d], 1);
    int slot = offsets[d] + pos;
    csr_src[slot] = ei[e];
    csr_ea[slot] = make_float2(ea[2 * e], ea[2 * e + 1]);
  } else {
    int n = (bb - 512) * 256 + threadIdx.x;
    int b = batch[n];
    if (n == 0) {
      for (int g = 0; g <= b; ++g) gstart[g] = 0;
    } else {
      int bp = batch[n - 1];
      for (int g = bp + 1; g <= b; ++g) gstart[g] = n;
    }
    if (n == N_NODES - 1) {
      for (int g = b + 1; g <= NGRAPH; ++g) gstart[g] = N_NODES;
    }
  }
}

// ---------------- fused MP layer (half-k per block + done-counter epilogue) --
// blockIdx = node-group*2 + khalf. Per block: G_NODES nodes, k-half of HID.
// Build S[g][kl][d] (regs->LDS, swizzled), contract with w2-half, reduce,
// write partial[khalf]. Second-finishing half (atomic done counter) performs
// the bias/deg/root/GRU epilogue for its node group.
__global__ __launch_bounds__(256, 4) void mp_kernel(
    const float* __restrict__ out_cur, float* __restrict__ out_nxt,
    const int* __restrict__ offsets, const float* __restrict__ deg_inv,
    const int* __restrict__ csr_src, const float2* __restrict__ csr_ea,
    const float* __restrict__ w1, const float* __restrict__ b1,
    const float* __restrict__ w2, const float* __restrict__ b2,
    const float* __restrict__ root_w, const float* __restrict__ conv_b,
    const float* __restrict__ gwih, const float* __restrict__ gwhh,
    const float* __restrict__ gbih, const float* __restrict__ gbhh,
    float* __restrict__ partial, float* __restrict__ O, int* __restrict__ done) {
  // S region: G*64*SROW = 9216 floats (36864 B). Aliased: staging
  // (hidb 64*HROW=4352f + osrcb 64*OROW=2304f = 6656f) and red (16*257=4112f).
  __shared__ float smem[G_NODES * KHALF * SROW];
  __shared__ float w1s[3 * KHALF];       // [w1x | w1y | b1] for this k-half
  __shared__ float ebuf[G_NODES * DIM];  // h rows (epilogue)
  __shared__ float mbuf[G_NODES * DIM];  // m rows (epilogue)
  __shared__ float obuf[G_NODES * DIM];  // O rows (epilogue)
  __shared__ int offs[G_NODES + 1];
  __shared__ int oldv;
  float* hidb = smem;
  float* osrcb = smem + CEDGE * HROW;
  float* S = smem;
  float* red = smem;

  const int t = threadIdx.x;
  const int bb = blockIdx.x;
  const int khalf = bb & 1;
  const int ng = bb >> 1;
  const int node0 = ng * G_NODES;

  if (t <= G_NODES) offs[t] = offsets[node0 + t];
  if (t < KHALF) {
    w1s[t] = w1[khalf * KHALF + t];
    w1s[KHALF + t] = w1[HID + khalf * KHALF + t];
    w1s[2 * KHALF + t] = b1[khalf * KHALF + t];
  }

  // build map: thread = (kg 0..15) x (dg 0..15); owns k0..k0+3, d0..d0+1
  const int kg = t >> 4, dg = t & 15;
  const int k0 = kg * 4, d0 = dg * 2;
  // staging map: edge slot ec (0..63), sub (0..3)
  const int ec = t >> 2, sub = t & 3;

  float acc[G_NODES][4][2];
#pragma unroll
  for (int g = 0; g < G_NODES; ++g)
#pragma unroll
    for (int i = 0; i < 4; ++i) { acc[g][i][0] = 0.0f; acc[g][i][1] = 0.0f; }
  float oacc[G_NODES] = {0.0f, 0.0f, 0.0f, 0.0f};
  __syncthreads();

  const int ebase = offs[0], eend = offs[G_NODES];
  for (int c0 = ebase; c0 < eend; c0 += CEDGE) {
    const int cnt = min(CEDGE, eend - c0);
    if (ec < cnt) {
      const int slot = c0 + ec;
      const float2 eav = csr_ea[slot];
      const int sidx = csr_src[slot];
#pragma unroll
      for (int q = 0; q < 4; ++q) {
        const int k4 = sub * 16 + q * 4;
        const float4 wx = *(const float4*)(w1s + k4);
        const float4 wy = *(const float4*)(w1s + KHALF + k4);
        const float4 bv = *(const float4*)(w1s + 2 * KHALF + k4);
        float4 hv;
        hv.x = fmaxf(fmaf(eav.y, wy.x, fmaf(eav.x, wx.x, bv.x)), 0.0f);
        hv.y = fmaxf(fmaf(eav.y, wy.y, fmaf(eav.x, wx.y, bv.y)), 0.0f);
        hv.z = fmaxf(fmaf(eav.y, wy.z, fmaf(eav.x, wx.z, bv.z)), 0.0f);
        hv.w = fmaxf(fmaf(eav.y, wy.w, fmaf(eav.x, wx.w, bv.w)), 0.0f);
        *(float4*)(hidb + ec * HROW + k4) = hv;
      }
      *(float4*)(osrcb + ec * OROW + sub * 8) =
          *(const float4*)(out_cur + sidx * DIM + sub * 8);
      *(float4*)(osrcb + ec * OROW + sub * 8 + 4) =
          *(const float4*)(out_cur + sidx * DIM + sub * 8 + 4);
    }
    __syncthreads();
#pragma unroll
    for (int g = 0; g < G_NODES; ++g) {
      const int es = max(offs[g], c0) - c0;
      const int ee = min(offs[g + 1], c0 + cnt) - c0;
      for (int e = es; e < ee; ++e) {
        const float4 hv = *(const float4*)(hidb + e * HROW + k0);
        const float2 ov = *(const float2*)(osrcb + e * OROW + d0);
        acc[g][0][0] = fmaf(hv.x, ov.x, acc[g][0][0]);
        acc[g][0][1] = fmaf(hv.x, ov.y, acc[g][0][1]);
        acc[g][1][0] = fmaf(hv.y, ov.x, acc[g][1][0]);
        acc[g][1][1] = fmaf(hv.y, ov.y, acc[g][1][1]);
        acc[g][2][0] = fmaf(hv.z, ov.x, acc[g][2][0]);
        acc[g][2][1] = fmaf(hv.z, ov.y, acc[g][2][1]);
        acc[g][3][0] = fmaf(hv.w, ov.x, acc[g][3][0]);
        acc[g][3][1] = fmaf(hv.w, ov.y, acc[g][3][1]);
        if (khalf == 0 && t < DIM) oacc[g] += osrcb[e * OROW + t];
      }
    }
    __syncthreads();  // builders done before next chunk's staging overwrite
  }

  if (khalf == 0 && t < DIM) {
#pragma unroll
    for (int g = 0; g < G_NODES; ++g) O[(node0 + g) * DIM + t] = oacc[g];
  }

  // dump S (swizzled: row kl, col (d + (kg&3)*8)&31)
  {
    const int dd = (d0 + (kg & 3) * 8) & 31;
#pragma unroll
    for (int g = 0; g < G_NODES; ++g) {
      float* Sg = S + g * KHALF * SROW;
#pragma unroll
      for (int i = 0; i < 4; ++i)
        *(float2*)(Sg + (k0 + i) * SROW + dd) = make_float2(acc[g][i][0], acc[g][i][1]);
    }
  }
  __syncthreads();

  // contract: thread = (ks 0..15, dvh 0..1, og 0..7)
  {
    const int ks = t >> 4;
    const int dvh = (t >> 3) & 1;
    const int og = t & 7;
    const int shift = (ks & 3) * 8;
    float a4[G_NODES][4];
#pragma unroll
    for (int g = 0; g < G_NODES; ++g)
#pragma unroll
      for (int r = 0; r < 4; ++r) a4[g][r] = 0.0f;
#pragma unroll
    for (int i = 0; i < 4; ++i) {
      const int kl = ks * 4 + i;
      const float* w2k = w2 + (size_t)(khalf * KHALF + kl) * (DIM * DIM);
#pragma unroll
      for (int q = 0; q < 4; ++q) {
        const int dbase = dvh * 16 + q * 4;
        const int dq = (dbase + shift) & 31;
        float4 sv[G_NODES];
#pragma unroll
        for (int g = 0; g < G_NODES; ++g)
          sv[g] = *(const float4*)(S + (g * KHALF + kl) * SROW + dq);
#pragma unroll
        for (int r = 0; r < 4; ++r) {
          const float4 wv = *(const float4*)(w2k + (dbase + r) * DIM + og * 4);
#pragma unroll
          for (int g = 0; g < G_NODES; ++g) {
            const float s = ((const float*)&sv[g])[r];
            a4[g][0] = fmaf(s, wv.x, a4[g][0]);
            a4[g][1] = fmaf(s, wv.y, a4[g][1]);
            a4[g][2] = fmaf(s, wv.z, a4[g][2]);
            a4[g][3] = fmaf(s, wv.w, a4[g][3]);
          }
        }
      }
    }
    __syncthreads();  // all S reads done; red may alias S
#pragma unroll
    for (int g = 0; g < G_NODES; ++g)
#pragma unroll
      for (int r = 0; r < 4; ++r) red[(g * 4 + r) * 257 + t] = a4[g][r];
  }
  __syncthreads();

  float sum = 0.0f;
  if (t < G_NODES * DIM) {
    const int g = t >> 5, o = t & 31;
    const float* rp = red + (g * 4 + (o & 3)) * 257 + (o >> 2);
#pragma unroll
    for (int j = 0; j < 32; ++j) sum += rp[j * 8];
    partial[(size_t)khalf * N_NODES * DIM + (node0 + g) * DIM + o] = sum;
  }
  __threadfence();
  if (t == 0) oldv = atomicAdd(done + ng, 1);
  __syncthreads();
  if (oldv != 1) return;  // first-finishing half exits; second does epilogue
  __threadfence();        // acquire: other half's partial/O now visible

  if (t < G_NODES * DIM) {
    ebuf[t] = out_cur[node0 * DIM + t];
    obuf[t] = O[node0 * DIM + t];
  }
  __syncthreads();
  if (t < G_NODES * DIM) {
    const int g = t >> 5, o = t & 31;
    const int node = node0 + g;
    float tot = sum + partial[(size_t)(1 - khalf) * N_NODES * DIM + node * DIM + o];
    float ob2 = 0.0f;
#pragma unroll
    for (int d = 0; d < DIM; ++d) ob2 = fmaf(obuf[g * DIM + d], b2[d * DIM + o], ob2);
    const float agg = (tot + ob2) * deg_inv[node];
    float rt = conv_b[o];
#pragma unroll
    for (int d = 0; d < DIM; ++d) rt = fmaf(ebuf[g * DIM + d], root_w[d * DIM + o], rt);
    mbuf[t] = fmaxf(agg + rt, 0.0f);
  }
  __syncthreads();
  if (t < G_NODES * DIM) {
    const int g = t >> 5, o = t & 31;
    const int node = node0 + g;
    float gi[3], gh[3];
#pragma unroll
    for (int jj = 0; jj < 3; ++jj) {
      float si = gbih[jj * DIM + o], sh = gbhh[jj * DIM + o];
#pragma unroll
      for (int d = 0; d < DIM; ++d) {
        si = fmaf(mbuf[g * DIM + d], gwih[d * 3 * DIM + jj * DIM + o], si);
        sh = fmaf(ebuf[g * DIM + d], gwhh[d * 3 * DIM + jj * DIM + o], sh);
      }
      gi[jj] = si;
      gh[jj] = sh;
    }
    const float r = sigmoidf_(gi[0] + gh[0]);
    const float z = sigmoidf_(gi[1] + gh[1]);
    const float nn = tanhf(fmaf(r, gh[2], gi[2]));
    out_nxt[node * DIM + o] = (1.0f - z) * nn + z * ebuf[t];
  }
}

// ---------------- Set2Set + head: one block per graph, LDS row cache -------
__global__ __launch_bounds__(256) void s2s_kernel(
    const float* __restrict__ outf, const int* __restrict__ gstart,
    const float* __restrict__ wih, const float* __restrict__ whh,
    const float* __restrict__ bih, const float* __restrict__ bhh,
    const float* __restrict__ l1w, const float* __restrict__ l1b,
    const float* __restrict__ l2w, const float* __restrict__ l2b,
    float* __restrict__ y) {
  __shared__ float rows[S2S_CAP * DIM];  // 48 KB node-row cache
  __shared__ float qh[DIM], qc[DIM], qstar[2 * DIM], gates[4 * DIM];
  __shared__ float wsum[4], wmax[4], wr[4][DIM];
  const int b = blockIdx.x, t = threadIdx.x;
  const int gs = gstart[b], ge = gstart[b + 1];
  const int cnt = ge - gs;
  const int w = t >> 6, lane = t & 63;
  const bool use_lds = (cnt <= S2S_CAP);
  if (use_lds) {
    for (int j = t * 4; j < cnt * DIM; j += 1024)
      *(float4*)(rows + j) = *(const float4*)(outf + (size_t)gs * DIM + j);
  }
  const float* R = use_lds ? (const float*)rows : outf + (size_t)gs * DIM;
  if (t < DIM) { qh[t] = 0.0f; qc[t] = 0.0f; }
  if (t < 2 * DIM) qstar[t] = 0.0f;
  __syncthreads();
  for (int step = 0; step < 3; ++step) {
    if (t < 4 * DIM) {
      float gv = bih[t] + bhh[t];
      for (int i = 0; i < 2 * DIM; ++i) gv = fmaf(qstar[i], wih[i * 4 * DIM + t], gv);
      for (int i = 0; i < DIM; ++i) gv = fmaf(qh[i], whh[i * 4 * DIM + t], gv);
      gates[t] = gv;
    }
    __syncthreads();
    if (t < DIM) {
      const float ig = sigmoidf_(gates[t]);
      const float fg = sigmoidf_(gates[DIM + t]);
      const float gg = tanhf(gates[2 * DIM + t]);
      const float og = sigmoidf_(gates[3 * DIM + t]);
      const float c = fmaf(fg, qc[t], ig * gg);
      qc[t] = c;
      qh[t] = og * tanhf(c);
    }
    __syncthreads();
    float lmax = -INFINITY;
    for (int n = t; n < cnt; n += 256) {
      const float* orow = R + n * DIM;
      float e = 0.0f;
#pragma unroll
      for (int d = 0; d < DIM; ++d) e = fmaf(orow[d], qh[d], e);
      lmax = fmaxf(lmax, e);
    }
#pragma unroll
    for (int off = 32; off > 0; off >>= 1) lmax = fmaxf(lmax, __shfl_xor(lmax, off));
    if (lane == 0) wmax[w] = lmax;
    __syncthreads();
    const float gmax = fmaxf(fmaxf(wmax[0], wmax[1]), fmaxf(wmax[2], wmax[3]));
    float rl[DIM];
#pragma unroll
    for (int d = 0; d < DIM; ++d) rl[d] = 0.0f;
    float lsum = 0.0f;
    for (int n = t; n < cnt; n += 256) {
      const float* orow = R + n * DIM;
      float e = 0.0f;
#pragma unroll
      for (int d = 0; d < DIM; ++d) e = fmaf(orow[d], qh[d], e);
      const float a = expf(e - gmax);
      lsum += a;
#pragma unroll
      for (int d = 0; d < DIM; ++d) rl[d] = fmaf(a, orow[d], rl[d]);
    }
#pragma unroll
    for (int off = 32; off > 0; off >>= 1) {
      lsum += __shfl_xor(lsum, off);
#pragma unroll
      for (int d = 0; d < DIM; ++d) rl[d] += __shfl_xor(rl[d], off);
    }
    __syncthreads();
    if (lane == 0) {
      wsum[w] = lsum;
#pragma unroll
      for (int d = 0; d < DIM; ++d) wr[w][d] = rl[d];
    }
    __syncthreads();
    if (t < DIM) {
      const float stot = wsum[0] + wsum[1] + wsum[2] + wsum[3];
      const float rv = wr[0][t] + wr[1][t] + wr[2][t] + wr[3][t];
      qstar[t] = qh[t];
      qstar[DIM + t] = (stot > 0.0f) ? rv / stot : 0.0f;
    }
    __syncthreads();
  }
  if (t < DIM) {
    float u = l1b[t];
    for (int i = 0; i < 2 * DIM; ++i) u = fmaf(qstar[i], l1w[i * DIM + t], u);
    u = fmaxf(u, 0.0f);
    float v = u * l2w[t];
#pragma unroll
    for (int off = 16; off > 0; off >>= 1) v += __shfl_xor(v, off);
    if (t == 0) y[b] = v + l2b[0];
  }
}

extern "C" void kernel_launch(void* const* d_in, const int* in_sizes, int n_in,
                              void* d_out, int out_size, void* d_ws, size_t ws_size,
                              hipStream_t stream) {
  const float* x        = (const float*)d_in[0];
  const float* ea       = (const float*)d_in[1];
  const float* lin0_w   = (const float*)d_in[2];
  const float* lin0_b   = (const float*)d_in[3];
  const float* enn_w1   = (const float*)d_in[4];
  const float* enn_b1   = (const float*)d_in[5];
  const float* enn_w2   = (const float*)d_in[6];
  const float* enn_b2   = (const float*)d_in[7];
  const float* root_w   = (const float*)d_in[8];
  const float* conv_b   = (const float*)d_in[9];
  const float* gru_wih  = (const float*)d_in[10];
  const float* gru_whh  = (const float*)d_in[11];
  const float* gru_bih  = (const float*)d_in[12];
  const float* gru_bhh  = (const float*)d_in[13];
  const float* s2s_wih  = (const float*)d_in[14];
  const float* s2s_whh  = (const float*)d_in[15];
  const float* s2s_bih  = (const float*)d_in[16];
  const float* s2s_bhh  = (const float*)d_in[17];
  const float* lin1_w   = (const float*)d_in[18];
  const float* lin1_b   = (const float*)d_in[19];
  const float* lin2_w   = (const float*)d_in[20];
  const float* lin2_b   = (const float*)d_in[21];
  const int*   ei       = (const int*)d_in[22];
  const int*   batch    = (const int*)d_in[23];
  float* y = (float*)d_out;

  const int ngroups = N_NODES / G_NODES;  // 2048

  char* p = (char*)d_ws;
  auto alloc = [&](size_t bytes) -> void* {
    void* r = (void*)p;
    p += (bytes + 255) & ~(size_t)255;
    return r;
  };
  float*  out_a   = (float*)alloc(N_NODES * DIM * 4);
  float*  out_b   = (float*)alloc(N_NODES * DIM * 4);
  // counts/cursor/done contiguous -> single memset
  int*    counts  = (int*)alloc(N_NODES * 4);
  int*    cursor  = (int*)alloc(N_NODES * 4);
  int*    done    = (int*)alloc((size_t)3 * ngroups * 4);
  int*    offsets = (int*)alloc((N_NODES + 1) * 4);
  int*    csr_src = (int*)alloc(N_EDGES * 4);
  float2* csr_ea  = (float2*)alloc(N_EDGES * 8);
  float*  deg_inv = (float*)alloc(N_NODES * 4);
  int*    gstart  = (int*)alloc((NGRAPH + 1) * 4);
  float*  Obuf    = (float*)alloc((size_t)N_NODES * DIM * 4);
  float*  partial = (float*)alloc((size_t)2 * N_NODES * DIM * 4);  // 2 MB
  (void)ws_size; (void)n_in; (void)in_sizes; (void)out_size;

  hipMemsetAsync(counts, 0, (size_t)(2 * N_NODES + 3 * ngroups) * 4, stream);

  prep1_kernel<<<1024 + 512, 256, 0, stream>>>(x, lin0_w, lin0_b, out_a,
                                               ei + N_EDGES, counts);
  scan_kernel<<<1, 1024, 0, stream>>>(counts, offsets, deg_inv);
  prep2_kernel<<<512 + 32, 256, 0, stream>>>(ei, ea, offsets, cursor, csr_src,
                                             csr_ea, batch, gstart);

  const float* cur = out_a;
  float* nxt = out_b;
  for (int layer = 0; layer < 3; ++layer) {
    mp_kernel<<<ngroups * 2, 256, 0, stream>>>(
        cur, nxt, offsets, deg_inv, csr_src, csr_ea, enn_w1, enn_b1, enn_w2,
        enn_b2, root_w, conv_b, gru_wih, gru_whh, gru_bih, gru_bhh,
        partial, Obuf, done + layer * ngroups);
    const float* tmp = cur; cur = nxt; nxt = (float*)tmp;
  }

  s2s_kernel<<<NGRAPH, 256, 0, stream>>>(cur, gstart, s2s_wih, s2s_whh, s2s_bih,
                                         s2s_bhh, lin1_w, lin1_b, lin2_w, lin2_b, y);
}

// Round 6
// 434.963 us; speedup vs baseline: 5.3845x; 5.3845x over previous
//
#include <hip/hip_runtime.h>

#define N_NODES 8192
#define N_EDGES 131072
#define NGRAPH  64
#define DIM     32
#define HID     128
#define KHALF   64         // k per pass
#define G_NODES 4          // nodes per block
#define SROW    36         // S d-stride (16B-aligned, used with d-rotation swizzle)
#define HROW    68         // hidb edge stride (bank-spread for staging writes)
#define OROW    36         // osrcb edge stride
#define CEDGE   64         // staged edges per chunk
#define S2S_CAP 384

__device__ __forceinline__ float sigmoidf_(float x) { return 1.0f / (1.0f + expf(-x)); }

// ---------------- prep ----------------
// blocks [0,1024): init node features; blocks [1024,1536): degree histogram
__global__ void prep1_kernel(const float* __restrict__ x, const float* __restrict__ w,
                             const float* __restrict__ b, float* __restrict__ out,
                             const int* __restrict__ dst, int* __restrict__ counts) {
  const int bb = blockIdx.x;
  if (bb < 1024) {
    int idx = bb * 256 + threadIdx.x;
    int n = idx >> 5, d = idx & 31;
    out[idx] = fmaxf(fmaf(x[n], w[d], b[d]), 0.0f);
  } else {
    int e = (bb - 1024) * 256 + threadIdx.x;
    atomicAdd(&counts[dst[e]], 1);
  }
}

__global__ void scan_kernel(const int* __restrict__ counts,
                            int* __restrict__ offsets,
                            float* __restrict__ deg_inv) {
  __shared__ int sm[1024];
  int t = threadIdx.x;
  int base = t * 8;
  int loc[8];
  int s = 0;
#pragma unroll
  for (int i = 0; i < 8; ++i) { loc[i] = s; s += counts[base + i]; }
  sm[t] = s;
  __syncthreads();
  for (int off = 1; off < 1024; off <<= 1) {
    int v = (t >= off) ? sm[t - off] : 0;
    __syncthreads();
    sm[t] += v;
    __syncthreads();
  }
  int excl = (t > 0) ? sm[t - 1] : 0;
#pragma unroll
  for (int i = 0; i < 8; ++i) {
    offsets[base + i] = excl + loc[i];
    int c = counts[base + i];
    deg_inv[base + i] = 1.0f / (float)(c > 0 ? c : 1);
  }
  if (t == 1023) offsets[N_NODES] = sm[1023];
}

// blocks [0,512): CSR scatter; blocks [512,544): graph-start table
__global__ void prep2_kernel(const int* __restrict__ ei, const float* __restrict__ ea,
                             const int* __restrict__ offsets, int* __restrict__ cursor,
                             int* __restrict__ csr_src, float2* __restrict__ csr_ea,
                             const int* __restrict__ batch, int* __restrict__ gstart) {
  const int bb = blockIdx.x;
  if (bb < 512) {
    int e = bb * 256 + threadIdx.x;
    int d = ei[N_EDGES + e];
    int pos = atomicAdd(&cursor[d], 1);
    int slot = offsets[d] + pos;
    csr_src[slot] = ei[e];
    csr_ea[slot] = make_float2(ea[2 * e], ea[2 * e + 1]);
  } else {
    int n = (bb - 512) * 256 + threadIdx.x;
    int b = batch[n];
    if (n == 0) {
      for (int g = 0; g <= b; ++g) gstart[g] = 0;
    } else {
      int bp = batch[n - 1];
      for (int g = bp + 1; g <= b; ++g) gstart[g] = n;
    }
    if (n == N_NODES - 1) {
      for (int g = b + 1; g <= NGRAPH; ++g) gstart[g] = N_NODES;
    }
  }
}

// ---------------- fully fused MP layer: one block = G_NODES nodes, full K ---
// Two sequential k-half passes per block; contract accumulator a4 persists in
// registers across passes; S / staging / reduction scratch all alias one LDS
// region. In-block epilogue (bias, deg, root, GRU). No cross-block traffic.
__global__ __launch_bounds__(256, 4) void mp_kernel(
    const float* __restrict__ out_cur, float* __restrict__ out_nxt,
    const int* __restrict__ offsets, const float* __restrict__ deg_inv,
    const int* __restrict__ csr_src, const float2* __restrict__ csr_ea,
    const float* __restrict__ w1, const float* __restrict__ b1,
    const float* __restrict__ w2, const float* __restrict__ b2,
    const float* __restrict__ root_w, const float* __restrict__ conv_b,
    const float* __restrict__ gwih, const float* __restrict__ gwhh,
    const float* __restrict__ gbih, const float* __restrict__ gbhh) {
  // S region: G*64*SROW = 9216 floats (36864 B). Aliased: staging
  // (hidb 64*HROW=4352f + osrcb 64*OROW=2304f = 6656f) and red (16*257=4112f).
  __shared__ float smem[G_NODES * KHALF * SROW];
  __shared__ float w1s[3 * HID];         // [w1x | w1y | b1], full K
  __shared__ float ebuf[G_NODES * DIM];  // h rows (epilogue)
  __shared__ float mbuf[G_NODES * DIM];  // m rows (epilogue)
  __shared__ float obuf[G_NODES * DIM];  // O rows (epilogue)
  __shared__ int offs[G_NODES + 1];
  float* hidb = smem;
  float* osrcb = smem + CEDGE * HROW;
  float* S = smem;
  float* red = smem;

  const int t = threadIdx.x;
  const int node0 = blockIdx.x * G_NODES;

  if (t <= G_NODES) offs[t] = offsets[node0 + t];
  if (t < HID) {
    w1s[t] = w1[t];
    w1s[HID + t] = w1[HID + t];
    w1s[2 * HID + t] = b1[t];
  }

  // build map: thread = (kg 0..15) x (dg 0..15); owns k0..k0+3 (local), d0..d0+1
  const int kg = t >> 4, dg = t & 15;
  const int k0 = kg * 4, d0 = dg * 2;
  // staging map: edge slot ec (0..63), sub (0..3)
  const int ec = t >> 2, sub = t & 3;
  // contract map: thread = (ks 0..15, dvh 0..1, og 0..7)
  const int ks = t >> 4;
  const int dvh = (t >> 3) & 1;
  const int og = t & 7;

  float a4[G_NODES][4];
#pragma unroll
  for (int g = 0; g < G_NODES; ++g)
#pragma unroll
    for (int r = 0; r < 4; ++r) a4[g][r] = 0.0f;
  float oacc[G_NODES] = {0.0f, 0.0f, 0.0f, 0.0f};
  __syncthreads();

  const int ebase = offs[0], eend = offs[G_NODES];

  for (int half = 0; half < 2; ++half) {
    float acc[G_NODES][4][2];
#pragma unroll
    for (int g = 0; g < G_NODES; ++g)
#pragma unroll
      for (int i = 0; i < 4; ++i) { acc[g][i][0] = 0.0f; acc[g][i][1] = 0.0f; }

    for (int c0 = ebase; c0 < eend; c0 += CEDGE) {
      const int cnt = min(CEDGE, eend - c0);
      if (ec < cnt) {
        const int slot = c0 + ec;
        const float2 eav = csr_ea[slot];
        const int sidx = csr_src[slot];
#pragma unroll
        for (int q = 0; q < 4; ++q) {
          const int kl = sub * 16 + q * 4;             // local k in half
          const int kgl = half * KHALF + kl;           // global k
          const float4 wx = *(const float4*)(w1s + kgl);
          const float4 wy = *(const float4*)(w1s + HID + kgl);
          const float4 bv = *(const float4*)(w1s + 2 * HID + kgl);
          float4 hv;
          hv.x = fmaxf(fmaf(eav.y, wy.x, fmaf(eav.x, wx.x, bv.x)), 0.0f);
          hv.y = fmaxf(fmaf(eav.y, wy.y, fmaf(eav.x, wx.y, bv.y)), 0.0f);
          hv.z = fmaxf(fmaf(eav.y, wy.z, fmaf(eav.x, wx.z, bv.z)), 0.0f);
          hv.w = fmaxf(fmaf(eav.y, wy.w, fmaf(eav.x, wx.w, bv.w)), 0.0f);
          *(float4*)(hidb + ec * HROW + kl) = hv;
        }
        *(float4*)(osrcb + ec * OROW + sub * 8) =
            *(const float4*)(out_cur + sidx * DIM + sub * 8);
        *(float4*)(osrcb + ec * OROW + sub * 8 + 4) =
            *(const float4*)(out_cur + sidx * DIM + sub * 8 + 4);
      }
      __syncthreads();
#pragma unroll
      for (int g = 0; g < G_NODES; ++g) {
        const int es = max(offs[g], c0) - c0;
        const int ee = min(offs[g + 1], c0 + cnt) - c0;
        for (int e = es; e < ee; ++e) {
          const float4 hv = *(const float4*)(hidb + e * HROW + k0);
          const float2 ov = *(const float2*)(osrcb + e * OROW + d0);
          acc[g][0][0] = fmaf(hv.x, ov.x, acc[g][0][0]);
          acc[g][0][1] = fmaf(hv.x, ov.y, acc[g][0][1]);
          acc[g][1][0] = fmaf(hv.y, ov.x, acc[g][1][0]);
          acc[g][1][1] = fmaf(hv.y, ov.y, acc[g][1][1]);
          acc[g][2][0] = fmaf(hv.z, ov.x, acc[g][2][0]);
          acc[g][2][1] = fmaf(hv.z, ov.y, acc[g][2][1]);
          acc[g][3][0] = fmaf(hv.w, ov.x, acc[g][3][0]);
          acc[g][3][1] = fmaf(hv.w, ov.y, acc[g][3][1]);
          if (half == 0 && t < DIM) oacc[g] += osrcb[e * OROW + t];
        }
      }
      __syncthreads();  // builders done before next chunk's staging overwrite
    }

    // dump S (swizzled: row kl, col (d + (kg&3)*8)&31); staging is dead
    {
      const int dd = (d0 + (kg & 3) * 8) & 31;
#pragma unroll
      for (int g = 0; g < G_NODES; ++g) {
        float* Sg = S + g * KHALF * SROW;
#pragma unroll
        for (int i = 0; i < 4; ++i)
          *(float2*)(Sg + (k0 + i) * SROW + dd) =
              make_float2(acc[g][i][0], acc[g][i][1]);
      }
    }
    __syncthreads();

    // contract this k-half into persistent a4
    {
      const int shift = (ks & 3) * 8;
#pragma unroll
      for (int i = 0; i < 4; ++i) {
        const int kl = ks * 4 + i;
        const float* w2k = w2 + (size_t)(half * KHALF + kl) * (DIM * DIM);
#pragma unroll
        for (int q = 0; q < 4; ++q) {
          const int dbase = dvh * 16 + q * 4;
          const int dq = (dbase + shift) & 31;
          float4 sv[G_NODES];
#pragma unroll
          for (int g = 0; g < G_NODES; ++g)
            sv[g] = *(const float4*)(S + (g * KHALF + kl) * SROW + dq);
#pragma unroll
          for (int r = 0; r < 4; ++r) {
            const float4 wv = *(const float4*)(w2k + (dbase + r) * DIM + og * 4);
#pragma unroll
            for (int g = 0; g < G_NODES; ++g) {
              const float s = ((const float*)&sv[g])[r];
              a4[g][0] = fmaf(s, wv.x, a4[g][0]);
              a4[g][1] = fmaf(s, wv.y, a4[g][1]);
              a4[g][2] = fmaf(s, wv.z, a4[g][2]);
              a4[g][3] = fmaf(s, wv.w, a4[g][3]);
            }
          }
        }
      }
    }
    __syncthreads();  // S reads done; next pass may restage over it
  }

  // cross-thread reduce via red (aliases S)
#pragma unroll
  for (int g = 0; g < G_NODES; ++g)
#pragma unroll
    for (int r = 0; r < 4; ++r) red[(g * 4 + r) * 257 + t] = a4[g][r];
  if (t < DIM) {
#pragma unroll
    for (int g = 0; g < G_NODES; ++g) obuf[g * DIM + t] = oacc[g];
  }
  if (t < G_NODES * DIM) ebuf[t] = out_cur[node0 * DIM + t];
  __syncthreads();

  // epilogue: t < 128 handles one (g,o) cell
  if (t < G_NODES * DIM) {
    const int g = t >> 5, o = t & 31;
    const int node = node0 + g;
    const float* rp = red + (g * 4 + (o & 3)) * 257 + (o >> 2);
    float sum = 0.0f;
#pragma unroll
    for (int j = 0; j < 32; ++j) sum += rp[j * 8];
    float ob2 = 0.0f;
#pragma unroll
    for (int d = 0; d < DIM; ++d) ob2 = fmaf(obuf[g * DIM + d], b2[d * DIM + o], ob2);
    const float agg = (sum + ob2) * deg_inv[node];
    float rt = conv_b[o];
#pragma unroll
    for (int d = 0; d < DIM; ++d) rt = fmaf(ebuf[g * DIM + d], root_w[d * DIM + o], rt);
    mbuf[t] = fmaxf(agg + rt, 0.0f);
  }
  __syncthreads();
  if (t < G_NODES * DIM) {
    const int g = t >> 5, o = t & 31;
    const int node = node0 + g;
    float gi[3], gh[3];
#pragma unroll
    for (int jj = 0; jj < 3; ++jj) {
      float si = gbih[jj * DIM + o], sh = gbhh[jj * DIM + o];
#pragma unroll
      for (int d = 0; d < DIM; ++d) {
        si = fmaf(mbuf[g * DIM + d], gwih[d * 3 * DIM + jj * DIM + o], si);
        sh = fmaf(ebuf[g * DIM + d], gwhh[d * 3 * DIM + jj * DIM + o], sh);
      }
      gi[jj] = si;
      gh[jj] = sh;
    }
    const float r = sigmoidf_(gi[0] + gh[0]);
    const float z = sigmoidf_(gi[1] + gh[1]);
    const float nn = tanhf(fmaf(r, gh[2], gi[2]));
    out_nxt[node * DIM + o] = (1.0f - z) * nn + z * ebuf[t];
  }
}

// ---------------- Set2Set + head: one block per graph, LDS row cache -------
__global__ __launch_bounds__(256) void s2s_kernel(
    const float* __restrict__ outf, const int* __restrict__ gstart,
    const float* __restrict__ wih, const float* __restrict__ whh,
    const float* __restrict__ bih, const float* __restrict__ bhh,
    const float* __restrict__ l1w, const float* __restrict__ l1b,
    const float* __restrict__ l2w, const float* __restrict__ l2b,
    float* __restrict__ y) {
  __shared__ float rows[S2S_CAP * DIM];  // 48 KB node-row cache
  __shared__ float qh[DIM], qc[DIM], qstar[2 * DIM], gates[4 * DIM];
  __shared__ float wsum[4], wmax[4], wr[4][DIM];
  const int b = blockIdx.x, t = threadIdx.x;
  const int gs = gstart[b], ge = gstart[b + 1];
  const int cnt = ge - gs;
  const int w = t >> 6, lane = t & 63;
  const bool use_lds = (cnt <= S2S_CAP);
  if (use_lds) {
    for (int j = t * 4; j < cnt * DIM; j += 1024)
      *(float4*)(rows + j) = *(const float4*)(outf + (size_t)gs * DIM + j);
  }
  const float* R = use_lds ? (const float*)rows : outf + (size_t)gs * DIM;
  if (t < DIM) { qh[t] = 0.0f; qc[t] = 0.0f; }
  if (t < 2 * DIM) qstar[t] = 0.0f;
  __syncthreads();
  for (int step = 0; step < 3; ++step) {
    if (t < 4 * DIM) {
      float gv = bih[t] + bhh[t];
      for (int i = 0; i < 2 * DIM; ++i) gv = fmaf(qstar[i], wih[i * 4 * DIM + t], gv);
      for (int i = 0; i < DIM; ++i) gv = fmaf(qh[i], whh[i * 4 * DIM + t], gv);
      gates[t] = gv;
    }
    __syncthreads();
    if (t < DIM) {
      const float ig = sigmoidf_(gates[t]);
      const float fg = sigmoidf_(gates[DIM + t]);
      const float gg = tanhf(gates[2 * DIM + t]);
      const float og = sigmoidf_(gates[3 * DIM + t]);
      const float c = fmaf(fg, qc[t], ig * gg);
      qc[t] = c;
      qh[t] = og * tanhf(c);
    }
    __syncthreads();
    float lmax = -INFINITY;
    for (int n = t; n < cnt; n += 256) {
      const float* orow = R + n * DIM;
      float e = 0.0f;
#pragma unroll
      for (int d = 0; d < DIM; ++d) e = fmaf(orow[d], qh[d], e);
      lmax = fmaxf(lmax, e);
    }
#pragma unroll
    for (int off = 32; off > 0; off >>= 1) lmax = fmaxf(lmax, __shfl_xor(lmax, off));
    if (lane == 0) wmax[w] = lmax;
    __syncthreads();
    const float gmax = fmaxf(fmaxf(wmax[0], wmax[1]), fmaxf(wmax[2], wmax[3]));
    float rl[DIM];
#pragma unroll
    for (int d = 0; d < DIM; ++d) rl[d] = 0.0f;
    float lsum = 0.0f;
    for (int n = t; n < cnt; n += 256) {
      const float* orow = R + n * DIM;
      float e = 0.0f;
#pragma unroll
      for (int d = 0; d < DIM; ++d) e = fmaf(orow[d], qh[d], e);
      const float a = expf(e - gmax);
      lsum += a;
#pragma unroll
      for (int d = 0; d < DIM; ++d) rl[d] = fmaf(a, orow[d], rl[d]);
    }
#pragma unroll
    for (int off = 32; off > 0; off >>= 1) {
      lsum += __shfl_xor(lsum, off);
#pragma unroll
      for (int d = 0; d < DIM; ++d) rl[d] += __shfl_xor(rl[d], off);
    }
    __syncthreads();
    if (lane == 0) {
      wsum[w] = lsum;
#pragma unroll
      for (int d = 0; d < DIM; ++d) wr[w][d] = rl[d];
    }
    __syncthreads();
    if (t < DIM) {
      const float stot = wsum[0] + wsum[1] + wsum[2] + wsum[3];
      const float rv = wr[0][t] + wr[1][t] + wr[2][t] + wr[3][t];
      qstar[t] = qh[t];
      qstar[DIM + t] = (stot > 0.0f) ? rv / stot : 0.0f;
    }
    __syncthreads();
  }
  if (t < DIM) {
    float u = l1b[t];
    for (int i = 0; i < 2 * DIM; ++i) u = fmaf(qstar[i], l1w[i * DIM + t], u);
    u = fmaxf(u, 0.0f);
    float v = u * l2w[t];
#pragma unroll
    for (int off = 16; off > 0; off >>= 1) v += __shfl_xor(v, off);
    if (t == 0) y[b] = v + l2b[0];
  }
}

extern "C" void kernel_launch(void* const* d_in, const int* in_sizes, int n_in,
                              void* d_out, int out_size, void* d_ws, size_t ws_size,
                              hipStream_t stream) {
  const float* x        = (const float*)d_in[0];
  const float* ea       = (const float*)d_in[1];
  const float* lin0_w   = (const float*)d_in[2];
  const float* lin0_b   = (const float*)d_in[3];
  const float* enn_w1   = (const float*)d_in[4];
  const float* enn_b1   = (const float*)d_in[5];
  const float* enn_w2   = (const float*)d_in[6];
  const float* enn_b2   = (const float*)d_in[7];
  const float* root_w   = (const float*)d_in[8];
  const float* conv_b   = (const float*)d_in[9];
  const float* gru_wih  = (const float*)d_in[10];
  const float* gru_whh  = (const float*)d_in[11];
  const float* gru_bih  = (const float*)d_in[12];
  const float* gru_bhh  = (const float*)d_in[13];
  const float* s2s_wih  = (const float*)d_in[14];
  const float* s2s_whh  = (const float*)d_in[15];
  const float* s2s_bih  = (const float*)d_in[16];
  const float* s2s_bhh  = (const float*)d_in[17];
  const float* lin1_w   = (const float*)d_in[18];
  const float* lin1_b   = (const float*)d_in[19];
  const float* lin2_w   = (const float*)d_in[20];
  const float* lin2_b   = (const float*)d_in[21];
  const int*   ei       = (const int*)d_in[22];
  const int*   batch    = (const int*)d_in[23];
  float* y = (float*)d_out;

  char* p = (char*)d_ws;
  auto alloc = [&](size_t bytes) -> void* {
    void* r = (void*)p;
    p += (bytes + 255) & ~(size_t)255;
    return r;
  };
  float*  out_a   = (float*)alloc(N_NODES * DIM * 4);
  float*  out_b   = (float*)alloc(N_NODES * DIM * 4);
  int*    counts  = (int*)alloc(N_NODES * 4);  // counts+cursor: one memset
  int*    cursor  = (int*)alloc(N_NODES * 4);
  int*    offsets = (int*)alloc((N_NODES + 1) * 4);
  int*    csr_src = (int*)alloc(N_EDGES * 4);
  float2* csr_ea  = (float2*)alloc(N_EDGES * 8);
  float*  deg_inv = (float*)alloc(N_NODES * 4);
  int*    gstart  = (int*)alloc((NGRAPH + 1) * 4);
  (void)ws_size; (void)n_in; (void)in_sizes; (void)out_size;

  hipMemsetAsync(counts, 0, (size_t)2 * N_NODES * 4, stream);

  prep1_kernel<<<1024 + 512, 256, 0, stream>>>(x, lin0_w, lin0_b, out_a,
                                               ei + N_EDGES, counts);
  scan_kernel<<<1, 1024, 0, stream>>>(counts, offsets, deg_inv);
  prep2_kernel<<<512 + 32, 256, 0, stream>>>(ei, ea, offsets, cursor, csr_src,
                                             csr_ea, batch, gstart);

  const int ngroups = N_NODES / G_NODES;  // 2048
  const float* cur = out_a;
  float* nxt = out_b;
  for (int layer = 0; layer < 3; ++layer) {
    mp_kernel<<<ngroups, 256, 0, stream>>>(
        cur, nxt, offsets, deg_inv, csr_src, csr_ea, enn_w1, enn_b1, enn_w2,
        enn_b2, root_w, conv_b, gru_wih, gru_whh, gru_bih, gru_bhh);
    const float* tmp = cur; cur = nxt; nxt = (float*)tmp;
  }

  s2s_kernel<<<NGRAPH, 256, 0, stream>>>(cur, gstart, s2s_wih, s2s_whh, s2s_bih,
                                         s2s_bhh, lin1_w, lin1_b, lin2_w, lin2_b, y);
}